// Round 1
// baseline (2941.566 us; speedup 1.0000x reference)
//
#include <hip/hip_runtime.h>

// ---------------------------------------------------------------------------
// EntropyCalculator: 2-layer post-norm transformer encoder + entropy head.
// B=256 S=512 D=128 H=4 HD=32 FF=512 V=256
// ---------------------------------------------------------------------------

#define AS1 __attribute__((address_space(1)))
#define AS3 __attribute__((address_space(3)))

typedef __bf16 bf16x8 __attribute__((ext_vector_type(8)));
typedef float  f32x4  __attribute__((ext_vector_type(4)));

__device__ __forceinline__ unsigned short f2bf(float f) {
  union { float f; unsigned int u; } c; c.f = f;
  unsigned int u = c.u;
  u += 0x7FFFu + ((u >> 16) & 1u);   // round-to-nearest-even
  return (unsigned short)(u >> 16);
}

__device__ __forceinline__ void async_copy16(const void* g, void* l) {
  // global -> LDS direct copy, 16B per lane, LDS dest = uniform base + lane*16
  __builtin_amdgcn_global_load_lds((AS1 void*)(void*)g, (AS3 void*)l, 16, 0, 0);
}

// ---------------------------------------------------------------------------
// f32 -> bf16 conversion (weights)
// ---------------------------------------------------------------------------
__global__ void f32_to_bf16(const float* __restrict__ src,
                            unsigned short* __restrict__ dst, int n) {
  int i = blockIdx.x * blockDim.x + threadIdx.x;
  if (i < n) dst[i] = f2bf(src[i]);
}

// ---------------------------------------------------------------------------
// Embedding + LayerNorm.  One wave per token (64 lanes x 2 dims).
// ---------------------------------------------------------------------------
__global__ __launch_bounds__(256) void embed_ln(
    const int* __restrict__ bytes, const float* __restrict__ emb,
    const float* __restrict__ pos, const float* __restrict__ g,
    const float* __restrict__ bta, float* __restrict__ h,
    unsigned short* __restrict__ hbf) {
  int wv = threadIdx.x >> 6, lane = threadIdx.x & 63;
  int tok = blockIdx.x * 4 + wv;
  int s = tok & 511;
  int bidx = bytes[tok];
  const float* e = emb + (size_t)bidx * 128;
  const float* p = pos + (size_t)s * 128;
  float x0 = e[lane] + p[lane];
  float x1 = e[lane + 64] + p[lane + 64];
  float sum = x0 + x1, ssq = x0 * x0 + x1 * x1;
#pragma unroll
  for (int off = 32; off; off >>= 1) {
    sum += __shfl_xor(sum, off);
    ssq += __shfl_xor(ssq, off);
  }
  float mean = sum * 0.0078125f;
  float var = ssq * 0.0078125f - mean * mean;
  float rs = rsqrtf(var + 1e-5f);
  float y0 = (x0 - mean) * rs * g[lane] + bta[lane];
  float y1 = (x1 - mean) * rs * g[lane + 64] + bta[lane + 64];
  size_t o = (size_t)tok * 128;
  h[o + lane] = y0; h[o + lane + 64] = y1;
  hbf[o + lane] = f2bf(y0); hbf[o + lane + 64] = f2bf(y1);
}

// ---------------------------------------------------------------------------
// Residual + LayerNorm (in place on h), also writes bf16 copy.
// ---------------------------------------------------------------------------
__global__ __launch_bounds__(256) void ln_res(
    float* h, const float* __restrict__ r, const float* __restrict__ g,
    const float* __restrict__ bta, unsigned short* __restrict__ hbf) {
  int wv = threadIdx.x >> 6, lane = threadIdx.x & 63;
  int tok = blockIdx.x * 4 + wv;
  size_t o = (size_t)tok * 128;
  float x0 = h[o + lane] + r[o + lane];
  float x1 = h[o + lane + 64] + r[o + lane + 64];
  float sum = x0 + x1, ssq = x0 * x0 + x1 * x1;
#pragma unroll
  for (int off = 32; off; off >>= 1) {
    sum += __shfl_xor(sum, off);
    ssq += __shfl_xor(ssq, off);
  }
  float mean = sum * 0.0078125f;
  float var = ssq * 0.0078125f - mean * mean;
  float rs = rsqrtf(var + 1e-5f);
  float y0 = (x0 - mean) * rs * g[lane] + bta[lane];
  float y1 = (x1 - mean) * rs * g[lane + 64] + bta[lane + 64];
  h[o + lane] = y0; h[o + lane + 64] = y1;
  hbf[o + lane] = f2bf(y0); hbf[o + lane + 64] = f2bf(y1);
}

// ---------------------------------------------------------------------------
// bf16 MFMA GEMM:  C[M,N] = A[M,K] @ W[N,K]^T + bias  (optional ReLU / bf16 out)
// 128x128 tile, BK=64, 4 waves, each wave 64x64 via 4x4 frags of 16x16x32.
// A, W row-major bf16; M%128==0, N%128==0, K%64==0.
// ---------------------------------------------------------------------------
template <int RELU, int OUTBF>
__global__ __launch_bounds__(256) void gemm_bf16(
    const unsigned short* __restrict__ A, const unsigned short* __restrict__ W,
    const float* __restrict__ bias, void* __restrict__ Cout,
    int M, int N, int K) {
  __shared__ __bf16 As[128 * 64];
  __shared__ __bf16 Ws[128 * 64];
  const int t = threadIdx.x;
  const int lane = t & 63, w = t >> 6;
  const int m0 = blockIdx.y * 128, n0 = blockIdx.x * 128;
  const int wm = (w >> 1) * 64, wn = (w & 1) * 64;
  f32x4 acc[4][4] = {};
  const int srow = w * 32 + (lane >> 3);  // staging row (j adds 8)
  const int scol = (lane & 7) * 8;        // staging col (elements)

  for (int k0 = 0; k0 < K; k0 += 64) {
#pragma unroll
    for (int j = 0; j < 4; ++j) {
      int r = srow + j * 8;
      int ldsrow = w * 32 + j * 8;
      async_copy16(A + (size_t)(m0 + r) * K + k0 + scol, &As[ldsrow * 64]);
      async_copy16(W + (size_t)(n0 + r) * K + k0 + scol, &Ws[ldsrow * 64]);
    }
    __syncthreads();
#pragma unroll
    for (int kk = 0; kk < 2; ++kk) {
      bf16x8 af[4], bfr[4];
#pragma unroll
      for (int f = 0; f < 4; ++f) {
        af[f]  = *(const bf16x8*)&As[(wm + f * 16 + (lane & 15)) * 64 + kk * 32 + (lane >> 4) * 8];
        bfr[f] = *(const bf16x8*)&Ws[(wn + f * 16 + (lane & 15)) * 64 + kk * 32 + (lane >> 4) * 8];
      }
#pragma unroll
      for (int fi = 0; fi < 4; ++fi)
#pragma unroll
        for (int fj = 0; fj < 4; ++fj)
          acc[fi][fj] = __builtin_amdgcn_mfma_f32_16x16x32_bf16(
              af[fi], bfr[fj], acc[fi][fj], 0, 0, 0);
    }
    __syncthreads();
  }

  // epilogue: D lane layout = col: lane&15, row: (lane>>4)*4 + reg
#pragma unroll
  for (int fj = 0; fj < 4; ++fj) {
    int col = n0 + wn + fj * 16 + (lane & 15);
    float bv = bias[col];
#pragma unroll
    for (int fi = 0; fi < 4; ++fi) {
#pragma unroll
      for (int r2 = 0; r2 < 4; ++r2) {
        int row = m0 + wm + fi * 16 + (lane >> 4) * 4 + r2;
        float v = acc[fi][fj][r2] + bv;
        if (RELU) v = fmaxf(v, 0.0f);
        if (OUTBF)
          ((unsigned short*)Cout)[(size_t)row * N + col] = f2bf(v);
        else
          ((float*)Cout)[(size_t)row * N + col] = v;
      }
    }
  }
}

// ---------------------------------------------------------------------------
// f32 attention over one batch-chunk of 64 batches.
// qkv: [64][512][384] f32 (q|k|v each 128, head h at h*32).
// One block = (b, head, half): 256 threads = 256 query rows, one row per lane.
// K/V staged in LDS in tiles of 128 keys. Online sum (no max needed: |s|~O(1)).
// Writes o as bf16 [64][512][128] at obf (chunk base).
// ---------------------------------------------------------------------------
__global__ __launch_bounds__(256) void attn_f32(
    const float* __restrict__ qkv, unsigned short* __restrict__ obf) {
  __shared__ float Ks[128][32];
  __shared__ float Vs[128][32];
  const int blk = blockIdx.x;
  const int half = blk & 1, hh = (blk >> 1) & 3, b = blk >> 3;
  const int lane = threadIdx.x & 63, wv = threadIdx.x >> 6;
  const int qrow = half * 256 + wv * 64 + lane;
  const float scale = 0.17677669529663687f;  // 1/sqrt(32)

  const float* qp = qkv + ((size_t)(b * 512 + qrow) * 384 + hh * 32);
  float q[32], acc[32];
#pragma unroll
  for (int i = 0; i < 8; ++i) {
    float4 v4 = *(const float4*)(qp + i * 4);
    q[i * 4 + 0] = v4.x * scale; q[i * 4 + 1] = v4.y * scale;
    q[i * 4 + 2] = v4.z * scale; q[i * 4 + 3] = v4.w * scale;
    acc[i * 4 + 0] = 0.f; acc[i * 4 + 1] = 0.f;
    acc[i * 4 + 2] = 0.f; acc[i * 4 + 3] = 0.f;
  }
  float l = 0.f;

  for (int tile = 0; tile < 4; ++tile) {
    for (int i = threadIdx.x; i < 128 * 32; i += 256) {
      int key = i >> 5, col = i & 31;
      const float* kg =
          qkv + ((size_t)(b * 512 + tile * 128 + key) * 384 + 128 + hh * 32 + col);
      Ks[key][col] = kg[0];
      Vs[key][col] = kg[128];
    }
    __syncthreads();
    for (int jj = 0; jj < 128; ++jj) {
      float dot = 0.f;
#pragma unroll
      for (int i2 = 0; i2 < 8; ++i2) {
        float4 k4 = *(const float4*)&Ks[jj][i2 * 4];
        dot += q[i2 * 4 + 0] * k4.x + q[i2 * 4 + 1] * k4.y +
               q[i2 * 4 + 2] * k4.z + q[i2 * 4 + 3] * k4.w;
      }
      float p = __expf(dot);
      l += p;
#pragma unroll
      for (int i2 = 0; i2 < 8; ++i2) {
        float4 v4 = *(const float4*)&Vs[jj][i2 * 4];
        acc[i2 * 4 + 0] += p * v4.x; acc[i2 * 4 + 1] += p * v4.y;
        acc[i2 * 4 + 2] += p * v4.z; acc[i2 * 4 + 3] += p * v4.w;
      }
    }
    __syncthreads();
  }
  float rl = 1.f / l;
  unsigned short* op = obf + ((size_t)(b * 512 + qrow) * 128 + hh * 32);
#pragma unroll
  for (int i = 0; i < 32; ++i) op[i] = f2bf(acc[i] * rl);
}

// ---------------------------------------------------------------------------
// Entropy from logits chunk [ntok][256].  One wave per token, 4 logits/lane.
// entropy = m + log(Z) - (sum e^(x-m) x)/Z
// ---------------------------------------------------------------------------
__global__ __launch_bounds__(256) void entropy_from_logits(
    const float* __restrict__ logits, float* __restrict__ ent) {
  int wv = threadIdx.x >> 6, lane = threadIdx.x & 63;
  int tok = blockIdx.x * 4 + wv;
  const float* lp = logits + (size_t)tok * 256;
  float4 x = *(const float4*)(lp + lane * 4);
  float m = fmaxf(fmaxf(x.x, x.y), fmaxf(x.z, x.w));
#pragma unroll
  for (int off = 32; off; off >>= 1) m = fmaxf(m, __shfl_xor(m, off));
  float e0 = __expf(x.x - m), e1 = __expf(x.y - m);
  float e2 = __expf(x.z - m), e3 = __expf(x.w - m);
  float z = e0 + e1 + e2 + e3;
  float sx = e0 * x.x + e1 * x.y + e2 * x.z + e3 * x.w;
#pragma unroll
  for (int off = 32; off; off >>= 1) {
    z += __shfl_xor(z, off);
    sx += __shfl_xor(sx, off);
  }
  if (lane == 0) ent[tok] = m + logf(z) - sx / z;
}

// ---------------------------------------------------------------------------
// avg over batch: out[s] = mean_b ent[b*512+s]
// ---------------------------------------------------------------------------
__global__ __launch_bounds__(64) void avg_entropy_kernel(
    const float* __restrict__ ent, float* __restrict__ out) {
  int s = blockIdx.x, lane = threadIdx.x;
  float a = 0.f;
  for (int b = lane; b < 256; b += 64) a += ent[(size_t)b * 512 + s];
#pragma unroll
  for (int off = 32; off; off >>= 1) a += __shfl_xor(a, off);
  if (lane == 0) out[s] = a * 0.00390625f;
}

// ---------------------------------------------------------------------------
// boundary + inclusive scan -> segment ids (written as float32)
// ---------------------------------------------------------------------------
__global__ __launch_bounds__(512) void seg_kernel(float* out) {
  __shared__ int cs[512];
  int i = threadIdx.x;
  float e = out[i];
  cs[i] = (i >= 1 && e > 4.0f) ? 1 : 0;
  __syncthreads();
  for (int off = 1; off < 512; off <<= 1) {
    int v = (i >= off) ? cs[i - off] : 0;
    __syncthreads();
    cs[i] += v;
    __syncthreads();
  }
  out[512 + i] = (float)cs[i];
}

// ---------------------------------------------------------------------------
// launch
// ---------------------------------------------------------------------------
extern "C" void kernel_launch(void* const* d_in, const int* in_sizes, int n_in,
                              void* d_out, int out_size, void* d_ws,
                              size_t ws_size, hipStream_t stream) {
  (void)in_sizes; (void)n_in; (void)out_size; (void)ws_size;
  const int*   input_bytes = (const int*)d_in[0];
  const float* emb    = (const float*)d_in[1];
  const float* pos    = (const float*)d_in[2];
  const float* ln_g   = (const float*)d_in[3];
  const float* ln_b   = (const float*)d_in[4];
  const float* attn_w = (const float*)d_in[5];
  const float* attn_b = (const float*)d_in[6];
  const float* out_w  = (const float*)d_in[7];
  const float* out_b  = (const float*)d_in[8];
  const float* ff1_w  = (const float*)d_in[9];
  const float* ff1_b  = (const float*)d_in[10];
  const float* ff2_w  = (const float*)d_in[11];
  const float* ff2_b  = (const float*)d_in[12];
  const float* n1_g   = (const float*)d_in[13];
  const float* n1_b   = (const float*)d_in[14];
  const float* n2_g   = (const float*)d_in[15];
  const float* n2_b   = (const float*)d_in[16];
  const float* proj_w = (const float*)d_in[17];
  const float* proj_b = (const float*)d_in[18];

  char* ws = (char*)d_ws;
  float*          h    = (float*)(ws);                        // 64 MB
  unsigned short* hbf  = (unsigned short*)(ws + 67108864);    // 32 MB
  float*          s1   = (float*)(ws + 100663296);            // 64 MB
  unsigned short* tbf  = (unsigned short*)(ws + 167772160);   // 32 MB
  unsigned short* wbf  = (unsigned short*)(ws + 201326592);   // ~0.85 MB
  float*          entb = (float*)(ws + 202178560);            // 0.5 MB

  unsigned short* attnw_bf = wbf;
  unsigned short* outw_bf  = wbf + 98304;
  unsigned short* ff1_bf   = wbf + 131072;
  unsigned short* ff2_bf   = wbf + 262144;
  unsigned short* projw_bf = wbf + 393216;

  f32_to_bf16<<<384, 256, 0, stream>>>(attn_w, attnw_bf, 98304);
  f32_to_bf16<<<128, 256, 0, stream>>>(out_w, outw_bf, 32768);
  f32_to_bf16<<<512, 256, 0, stream>>>(ff1_w, ff1_bf, 131072);
  f32_to_bf16<<<512, 256, 0, stream>>>(ff2_w, ff2_bf, 131072);
  f32_to_bf16<<<128, 256, 0, stream>>>(proj_w, projw_bf, 32768);

  embed_ln<<<32768, 256, 0, stream>>>(input_bytes, emb, pos, ln_g, ln_b, h, hbf);

  for (int l = 0; l < 2; ++l) {
    // QKV + attention, in 4 batch-chunks of 64
    for (int bc = 0; bc < 4; ++bc) {
      gemm_bf16<0, 0><<<dim3(3, 256), 256, 0, stream>>>(
          hbf + (size_t)bc * 32768 * 128, attnw_bf + l * 49152,
          attn_b + l * 384, s1, 32768, 384, 128);
      attn_f32<<<512, 256, 0, stream>>>(s1, tbf + (size_t)bc * 32768 * 128);
    }
    // output projection over all tokens
    gemm_bf16<0, 0><<<dim3(1, 1024), 256, 0, stream>>>(
        tbf, outw_bf + l * 16384, out_b + l * 128, s1, 131072, 128, 128);
    ln_res<<<32768, 256, 0, stream>>>(h, s1, n1_g + l * 128, n1_b + l * 128, hbf);
    // FFN in 8 token-chunks of 16384
    for (int tc = 0; tc < 8; ++tc) {
      gemm_bf16<1, 1><<<dim3(4, 128), 256, 0, stream>>>(
          hbf + (size_t)tc * 16384 * 128, ff1_bf + l * 65536,
          ff1_b + l * 512, tbf, 16384, 512, 128);
      gemm_bf16<0, 0><<<dim3(1, 128), 256, 0, stream>>>(
          tbf, ff2_bf + l * 65536, ff2_b + l * 128,
          s1 + (size_t)tc * 16384 * 128, 16384, 128, 512);
    }
    ln_res<<<32768, 256, 0, stream>>>(h, s1, n2_g + l * 128, n2_b + l * 128, hbf);
  }

  // projection to vocab + entropy, 8 token-chunks
  for (int tc = 0; tc < 8; ++tc) {
    gemm_bf16<0, 0><<<dim3(2, 128), 256, 0, stream>>>(
        hbf + (size_t)tc * 16384 * 128, projw_bf, proj_b, s1, 16384, 256, 128);
    entropy_from_logits<<<4096, 256, 0, stream>>>(s1, entb + (size_t)tc * 16384);
  }
  avg_entropy_kernel<<<512, 64, 0, stream>>>(entb, (float*)d_out);
  seg_kernel<<<1, 512, 0, stream>>>((float*)d_out);
}

// Round 2
// 896.156 us; speedup vs baseline: 3.2824x; 3.2824x over previous
//
#include <hip/hip_runtime.h>

// ---------------------------------------------------------------------------
// EntropyCalculator: 2-layer post-norm transformer encoder + entropy head.
// B=256 S=512 D=128 H=4 HD=32 FF=512 V=256
// ---------------------------------------------------------------------------

#define AS1 __attribute__((address_space(1)))
#define AS3 __attribute__((address_space(3)))

typedef __bf16 bf16x8 __attribute__((ext_vector_type(8)));
typedef __bf16 bf16x4 __attribute__((ext_vector_type(4)));
typedef float  f32x4  __attribute__((ext_vector_type(4)));

__device__ __forceinline__ unsigned short f2bf(float f) {
  union { float f; unsigned int u; } c; c.f = f;
  unsigned int u = c.u;
  u += 0x7FFFu + ((u >> 16) & 1u);   // round-to-nearest-even
  return (unsigned short)(u >> 16);
}

__device__ __forceinline__ void async_copy16(const void* g, void* l) {
  __builtin_amdgcn_global_load_lds((AS1 void*)(void*)g, (AS3 void*)l, 16, 0, 0);
}

// ---------------------------------------------------------------------------
__global__ void f32_to_bf16(const float* __restrict__ src,
                            unsigned short* __restrict__ dst, int n) {
  int i = blockIdx.x * blockDim.x + threadIdx.x;
  if (i < n) dst[i] = f2bf(src[i]);
}

// ---------------------------------------------------------------------------
// Embedding + LayerNorm.  One wave per token.
// ---------------------------------------------------------------------------
__global__ __launch_bounds__(256) void embed_ln(
    const int* __restrict__ bytes, const float* __restrict__ emb,
    const float* __restrict__ pos, const float* __restrict__ g,
    const float* __restrict__ bta, float* __restrict__ h,
    unsigned short* __restrict__ hbf) {
  int wv = threadIdx.x >> 6, lane = threadIdx.x & 63;
  int tok = blockIdx.x * 4 + wv;
  int s = tok & 511;
  int bidx = bytes[tok];
  const float* e = emb + (size_t)bidx * 128;
  const float* p = pos + (size_t)s * 128;
  float x0 = e[lane] + p[lane];
  float x1 = e[lane + 64] + p[lane + 64];
  float sum = x0 + x1, ssq = x0 * x0 + x1 * x1;
#pragma unroll
  for (int off = 32; off; off >>= 1) {
    sum += __shfl_xor(sum, off);
    ssq += __shfl_xor(ssq, off);
  }
  float mean = sum * 0.0078125f;
  float var = ssq * 0.0078125f - mean * mean;
  float rs = rsqrtf(var + 1e-5f);
  float y0 = (x0 - mean) * rs * g[lane] + bta[lane];
  float y1 = (x1 - mean) * rs * g[lane + 64] + bta[lane + 64];
  size_t o = (size_t)tok * 128;
  h[o + lane] = y0; h[o + lane + 64] = y1;
  hbf[o + lane] = f2bf(y0); hbf[o + lane + 64] = f2bf(y1);
}

// ---------------------------------------------------------------------------
// Residual + LayerNorm (in place on h), also writes bf16 copy.
// ---------------------------------------------------------------------------
__global__ __launch_bounds__(256) void ln_res(
    float* h, const float* __restrict__ r, const float* __restrict__ g,
    const float* __restrict__ bta, unsigned short* __restrict__ hbf) {
  int wv = threadIdx.x >> 6, lane = threadIdx.x & 63;
  int tok = blockIdx.x * 4 + wv;
  size_t o = (size_t)tok * 128;
  float x0 = h[o + lane] + r[o + lane];
  float x1 = h[o + lane + 64] + r[o + lane + 64];
  float sum = x0 + x1, ssq = x0 * x0 + x1 * x1;
#pragma unroll
  for (int off = 32; off; off >>= 1) {
    sum += __shfl_xor(sum, off);
    ssq += __shfl_xor(ssq, off);
  }
  float mean = sum * 0.0078125f;
  float var = ssq * 0.0078125f - mean * mean;
  float rs = rsqrtf(var + 1e-5f);
  float y0 = (x0 - mean) * rs * g[lane] + bta[lane];
  float y1 = (x1 - mean) * rs * g[lane + 64] + bta[lane + 64];
  h[o + lane] = y0; h[o + lane + 64] = y1;
  hbf[o + lane] = f2bf(y0); hbf[o + lane + 64] = f2bf(y1);
}

// ---------------------------------------------------------------------------
// bf16 MFMA GEMM:  C[M,N] = A[M,K] @ W[N,K]^T + bias
// 128x128 tile, BK=64, 4 waves, each wave 64x64 via 4x4 frags of 16x16x32.
// ---------------------------------------------------------------------------
template <int RELU, int OUTBF>
__global__ __launch_bounds__(256) void gemm_bf16(
    const unsigned short* __restrict__ A, const unsigned short* __restrict__ W,
    const float* __restrict__ bias, void* __restrict__ Cout,
    int M, int N, int K) {
  __shared__ __bf16 As[128 * 64];
  __shared__ __bf16 Ws[128 * 64];
  const int t = threadIdx.x;
  const int lane = t & 63, w = t >> 6;
  const int m0 = blockIdx.y * 128, n0 = blockIdx.x * 128;
  const int wm = (w >> 1) * 64, wn = (w & 1) * 64;
  f32x4 acc[4][4] = {};
  const int srow = w * 32 + (lane >> 3);
  const int scol = (lane & 7) * 8;

  for (int k0 = 0; k0 < K; k0 += 64) {
#pragma unroll
    for (int j = 0; j < 4; ++j) {
      int r = srow + j * 8;
      int ldsrow = w * 32 + j * 8;
      async_copy16(A + (size_t)(m0 + r) * K + k0 + scol, &As[ldsrow * 64]);
      async_copy16(W + (size_t)(n0 + r) * K + k0 + scol, &Ws[ldsrow * 64]);
    }
    __syncthreads();
#pragma unroll
    for (int kk = 0; kk < 2; ++kk) {
      bf16x8 af[4], bfr[4];
#pragma unroll
      for (int f = 0; f < 4; ++f) {
        af[f]  = *(const bf16x8*)&As[(wm + f * 16 + (lane & 15)) * 64 + kk * 32 + (lane >> 4) * 8];
        bfr[f] = *(const bf16x8*)&Ws[(wn + f * 16 + (lane & 15)) * 64 + kk * 32 + (lane >> 4) * 8];
      }
#pragma unroll
      for (int fi = 0; fi < 4; ++fi)
#pragma unroll
        for (int fj = 0; fj < 4; ++fj)
          acc[fi][fj] = __builtin_amdgcn_mfma_f32_16x16x32_bf16(
              af[fi], bfr[fj], acc[fi][fj], 0, 0, 0);
    }
    __syncthreads();
  }

#pragma unroll
  for (int fj = 0; fj < 4; ++fj) {
    int col = n0 + wn + fj * 16 + (lane & 15);
    float bv = bias[col];
#pragma unroll
    for (int fi = 0; fi < 4; ++fi) {
#pragma unroll
      for (int r2 = 0; r2 < 4; ++r2) {
        int row = m0 + wm + fi * 16 + (lane >> 4) * 4 + r2;
        float v = acc[fi][fj][r2] + bv;
        if (RELU) v = fmaxf(v, 0.0f);
        if (OUTBF)
          ((unsigned short*)Cout)[(size_t)row * N + col] = f2bf(v);
        else
          ((float*)Cout)[(size_t)row * N + col] = v;
      }
    }
  }
}

// ---------------------------------------------------------------------------
// MFMA flash attention.  One block (512 thr = 8 waves) per (batch, head).
// qkv bf16 [65536, 384] chunk-local; head hh: q @ hh*32, k @ 128+hh*32,
// v @ 256+hh*32.  Each wave owns 64 query rows; loops 8 key tiles of 64.
// S^T = mfma(K_frag, Q_frag): lane holds query col c=lane&15, keys g*4+r.
// exp (no max; scores O(1)), pack 4 keys -> b64 write to per-wave P LDS,
// PV = mfma(P_frag, Vt_frag).  l reduced across g-groups at the end.
// LDS: Ks[512][40] + Vt[32][520] + P[8][64][80] = 156160 B.
// ---------------------------------------------------------------------------
__global__ __launch_bounds__(512) void attn_mfma(
    const unsigned short* __restrict__ qkv, unsigned short* __restrict__ obf) {
  extern __shared__ char smem[];
  __bf16* Ks = (__bf16*)smem;                 // [512][40]
  __bf16* Vt = (__bf16*)(smem + 40960);       // [32][520]
  __bf16* Pl = (__bf16*)(smem + 74240);       // [8][64][80]

  const int hh = blockIdx.x & 3, bl = blockIdx.x >> 2;
  const int t = threadIdx.x;
  const int lane = t & 63, wv = t >> 6;
  const int c = lane & 15, g = lane >> 4;
  const size_t tok0 = (size_t)bl * 512;

  // ---- stage K rows and V^T ----
  {
    const unsigned short* kr = qkv + (tok0 + t) * 384 + 128 + hh * 32;
    bf16x8 k0 = *(const bf16x8*)(kr);
    bf16x8 k1 = *(const bf16x8*)(kr + 8);
    bf16x8 k2 = *(const bf16x8*)(kr + 16);
    bf16x8 k3 = *(const bf16x8*)(kr + 24);
    __bf16* kd = Ks + t * 40;
    *(bf16x8*)(kd + 0) = k0;  *(bf16x8*)(kd + 8) = k1;
    *(bf16x8*)(kd + 16) = k2; *(bf16x8*)(kd + 24) = k3;
    const unsigned short* vr = kr + 128;
    bf16x8 v0 = *(const bf16x8*)(vr);
    bf16x8 v1 = *(const bf16x8*)(vr + 8);
    bf16x8 v2 = *(const bf16x8*)(vr + 16);
    bf16x8 v3 = *(const bf16x8*)(vr + 24);
#pragma unroll
    for (int i = 0; i < 8; ++i) {
      Vt[(i)      * 520 + t] = v0[i];
      Vt[(i + 8)  * 520 + t] = v1[i];
      Vt[(i + 16) * 520 + t] = v2[i];
      Vt[(i + 24) * 520 + t] = v3[i];
    }
  }

  // ---- Q fragments (b-operand): lane holds Q[qf*16+c][g*8 .. g*8+7] ----
  bf16x8 qb[4];
  {
    const unsigned short* qp = qkv + (tok0 + wv * 64) * 384 + hh * 32;
#pragma unroll
    for (int qf = 0; qf < 4; ++qf)
      qb[qf] = *(const bf16x8*)(qp + (size_t)(qf * 16 + c) * 384 + g * 8);
  }
  __syncthreads();

  f32x4 o[4][2] = {};
  float l[4] = {0.f, 0.f, 0.f, 0.f};
  __bf16* Pw = Pl + wv * (64 * 80);
  const float sc = 0.17677669529663687f;  // 1/sqrt(32)

  for (int kt = 0; kt < 8; ++kt) {
    // K fragments (a-operand): lane holds K[kt*64+kf*16+c][g*8 ..]
    bf16x8 ka[4];
#pragma unroll
    for (int kf = 0; kf < 4; ++kf)
      ka[kf] = *(const bf16x8*)&Ks[(kt * 64 + kf * 16 + c) * 40 + g * 8];
    f32x4 s[4][4];
#pragma unroll
    for (int qf = 0; qf < 4; ++qf)
#pragma unroll
      for (int kf = 0; kf < 4; ++kf) {
        f32x4 z = {0.f, 0.f, 0.f, 0.f};
        s[qf][kf] =
            __builtin_amdgcn_mfma_f32_16x16x32_bf16(ka[kf], qb[qf], z, 0, 0, 0);
      }
    // exp + pack to per-wave P LDS: P[q_local][key_local], stride 80
#pragma unroll
    for (int qf = 0; qf < 4; ++qf) {
      float lq = 0.f;
#pragma unroll
      for (int kf = 0; kf < 4; ++kf) {
        float p0 = __expf(s[qf][kf][0] * sc);
        float p1 = __expf(s[qf][kf][1] * sc);
        float p2 = __expf(s[qf][kf][2] * sc);
        float p3 = __expf(s[qf][kf][3] * sc);
        lq += (p0 + p1) + (p2 + p3);
        bf16x4 pk;
        pk[0] = (__bf16)p0; pk[1] = (__bf16)p1;
        pk[2] = (__bf16)p2; pk[3] = (__bf16)p3;
        *(bf16x4*)&Pw[(qf * 16 + c) * 80 + kf * 16 + g * 4] = pk;
      }
      l[qf] += lq;
    }
    asm volatile("s_waitcnt lgkmcnt(0)" ::: "memory");  // cross-lane P visible
#pragma unroll
    for (int ksl = 0; ksl < 2; ++ksl) {
      bf16x8 vb[2];
#pragma unroll
      for (int hf = 0; hf < 2; ++hf)
        vb[hf] = *(const bf16x8*)&Vt[(hf * 16 + c) * 520 + kt * 64 + ksl * 32 + g * 8];
#pragma unroll
      for (int qf = 0; qf < 4; ++qf) {
        bf16x8 pa = *(const bf16x8*)&Pw[(qf * 16 + c) * 80 + ksl * 32 + g * 8];
#pragma unroll
        for (int hf = 0; hf < 2; ++hf)
          o[qf][hf] = __builtin_amdgcn_mfma_f32_16x16x32_bf16(pa, vb[hf],
                                                              o[qf][hf], 0, 0, 0);
      }
    }
    asm volatile("" ::: "memory");  // keep next tile's P writes after reads
  }

#pragma unroll
  for (int qf = 0; qf < 4; ++qf) {
    l[qf] += __shfl_xor(l[qf], 16);
    l[qf] += __shfl_xor(l[qf], 32);
  }
  unsigned short* op = obf + (tok0 + wv * 64) * 128 + hh * 32;
#pragma unroll
  for (int qf = 0; qf < 4; ++qf) {
#pragma unroll
    for (int r = 0; r < 4; ++r) {
      float lv = __shfl(l[qf], g * 4 + r);  // reduced l for query qf*16+g*4+r
      float rl = 1.0f / lv;
#pragma unroll
      for (int hf = 0; hf < 2; ++hf)
        op[(size_t)(qf * 16 + g * 4 + r) * 128 + hf * 16 + c] =
            f2bf(o[qf][hf][r] * rl);
    }
  }
}

// ---------------------------------------------------------------------------
// Entropy from logits chunk [ntok][256].  One wave per token.
// ---------------------------------------------------------------------------
__global__ __launch_bounds__(256) void entropy_from_logits(
    const float* __restrict__ logits, float* __restrict__ ent) {
  int wv = threadIdx.x >> 6, lane = threadIdx.x & 63;
  int tok = blockIdx.x * 4 + wv;
  const float* lp = logits + (size_t)tok * 256;
  float4 x = *(const float4*)(lp + lane * 4);
  float m = fmaxf(fmaxf(x.x, x.y), fmaxf(x.z, x.w));
#pragma unroll
  for (int off = 32; off; off >>= 1) m = fmaxf(m, __shfl_xor(m, off));
  float e0 = __expf(x.x - m), e1 = __expf(x.y - m);
  float e2 = __expf(x.z - m), e3 = __expf(x.w - m);
  float z = e0 + e1 + e2 + e3;
  float sx = e0 * x.x + e1 * x.y + e2 * x.z + e3 * x.w;
#pragma unroll
  for (int off = 32; off; off >>= 1) {
    z += __shfl_xor(z, off);
    sx += __shfl_xor(sx, off);
  }
  if (lane == 0) ent[tok] = m + logf(z) - sx / z;
}

__global__ __launch_bounds__(64) void avg_entropy_kernel(
    const float* __restrict__ ent, float* __restrict__ out) {
  int s = blockIdx.x, lane = threadIdx.x;
  float a = 0.f;
  for (int b = lane; b < 256; b += 64) a += ent[(size_t)b * 512 + s];
#pragma unroll
  for (int off = 32; off; off >>= 1) a += __shfl_xor(a, off);
  if (lane == 0) out[s] = a * 0.00390625f;
}

__global__ __launch_bounds__(512) void seg_kernel(float* out) {
  __shared__ int cs[512];
  int i = threadIdx.x;
  float e = out[i];
  cs[i] = (i >= 1 && e > 4.0f) ? 1 : 0;
  __syncthreads();
  for (int off = 1; off < 512; off <<= 1) {
    int v = (i >= off) ? cs[i - off] : 0;
    __syncthreads();
    cs[i] += v;
    __syncthreads();
  }
  out[512 + i] = (float)cs[i];
}

// ---------------------------------------------------------------------------
extern "C" void kernel_launch(void* const* d_in, const int* in_sizes, int n_in,
                              void* d_out, int out_size, void* d_ws,
                              size_t ws_size, hipStream_t stream) {
  (void)in_sizes; (void)n_in; (void)out_size; (void)ws_size;
  const int*   input_bytes = (const int*)d_in[0];
  const float* emb    = (const float*)d_in[1];
  const float* pos    = (const float*)d_in[2];
  const float* ln_g   = (const float*)d_in[3];
  const float* ln_b   = (const float*)d_in[4];
  const float* attn_w = (const float*)d_in[5];
  const float* attn_b = (const float*)d_in[6];
  const float* out_w  = (const float*)d_in[7];
  const float* out_b  = (const float*)d_in[8];
  const float* ff1_w  = (const float*)d_in[9];
  const float* ff1_b  = (const float*)d_in[10];
  const float* ff2_w  = (const float*)d_in[11];
  const float* ff2_b  = (const float*)d_in[12];
  const float* n1_g   = (const float*)d_in[13];
  const float* n1_b   = (const float*)d_in[14];
  const float* n2_g   = (const float*)d_in[15];
  const float* n2_b   = (const float*)d_in[16];
  const float* proj_w = (const float*)d_in[17];
  const float* proj_b = (const float*)d_in[18];

  char* ws = (char*)d_ws;
  float*          h      = (float*)(ws);                      // 64 MB
  unsigned short* hbf    = (unsigned short*)(ws + 67108864);  // 32 MB
  char*           Cr     = ws + 100663296;                    // 98 MB scratch
  unsigned short* obf    = (unsigned short*)Cr;               // 32 MB
  unsigned short* qkvc   = (unsigned short*)(Cr + 33554432);  // 50.3 MB (attn)
  float*          s1     = (float*)(Cr + 33554432);           // 64 MB (post)
  unsigned short* ff1t   = (unsigned short*)Cr;               // 33.5 MB (ffn)
  float*          logits = (float*)Cr;                        // 33.5 MB (final)
  unsigned short* wbf    = (unsigned short*)(ws + 203423744);
  float*          entb   = (float*)(ws + 204283904);          // 0.5 MB

  unsigned short* attnw_bf = wbf;
  unsigned short* outw_bf  = wbf + 98304;
  unsigned short* ff1_bf   = wbf + 131072;
  unsigned short* ff2_bf   = wbf + 262144;
  unsigned short* projw_bf = wbf + 393216;

  f32_to_bf16<<<384, 256, 0, stream>>>(attn_w, attnw_bf, 98304);
  f32_to_bf16<<<128, 256, 0, stream>>>(out_w, outw_bf, 32768);
  f32_to_bf16<<<512, 256, 0, stream>>>(ff1_w, ff1_bf, 131072);
  f32_to_bf16<<<512, 256, 0, stream>>>(ff2_w, ff2_bf, 131072);
  f32_to_bf16<<<128, 256, 0, stream>>>(proj_w, projw_bf, 32768);

  embed_ln<<<32768, 256, 0, stream>>>(input_bytes, emb, pos, ln_g, ln_b, h, hbf);

  for (int l = 0; l < 2; ++l) {
    // QKV GEMM (bf16 out) + MFMA attention, 2 batch-chunks of 128 batches
    for (int ch = 0; ch < 2; ++ch) {
      gemm_bf16<0, 1><<<dim3(3, 512), 256, 0, stream>>>(
          hbf + (size_t)ch * 65536 * 128, attnw_bf + l * 49152,
          attn_b + l * 384, qkvc, 65536, 384, 128);
      attn_mfma<<<512, 512, 156160, stream>>>(qkvc,
                                              obf + (size_t)ch * 65536 * 128);
    }
    // output projection over all tokens (f32 out for residual)
    gemm_bf16<0, 0><<<dim3(1, 1024), 256, 0, stream>>>(
        obf, outw_bf + l * 16384, out_b + l * 128, s1, 131072, 128, 128);
    ln_res<<<32768, 256, 0, stream>>>(h, s1, n1_g + l * 128, n1_b + l * 128, hbf);
    // FFN in 4 token-chunks of 32768
    for (int tc = 0; tc < 4; ++tc) {
      gemm_bf16<1, 1><<<dim3(4, 256), 256, 0, stream>>>(
          hbf + (size_t)tc * 32768 * 128, ff1_bf + l * 65536,
          ff1_b + l * 512, ff1t, 32768, 512, 128);
      gemm_bf16<0, 0><<<dim3(1, 256), 256, 0, stream>>>(
          ff1t, ff2_bf + l * 65536, ff2_b + l * 128,
          s1 + (size_t)tc * 32768 * 128, 32768, 128, 512);
    }
    ln_res<<<32768, 256, 0, stream>>>(h, s1, n2_g + l * 128, n2_b + l * 128, hbf);
  }

  // vocab projection + entropy, 4 token-chunks
  for (int tc = 0; tc < 4; ++tc) {
    gemm_bf16<0, 0><<<dim3(2, 256), 256, 0, stream>>>(
        hbf + (size_t)tc * 32768 * 128, projw_bf, proj_b, logits, 32768, 256, 128);
    entropy_from_logits<<<8192, 256, 0, stream>>>(logits,
                                                  entb + (size_t)tc * 32768);
  }
  avg_entropy_kernel<<<512, 64, 0, stream>>>(entb, (float*)d_out);
  seg_kernel<<<1, 512, 0, stream>>>((float*)d_out);
}